// Round 1
// baseline (219.964 us; speedup 1.0000x reference)
//
#include <hip/hip_runtime.h>

#define B_DIM 8
#define T_DIM 2048
#define C_DIM 1024
#define H_DIM 128

typedef __attribute__((ext_vector_type(8))) short bf16x8;
typedef __attribute__((ext_vector_type(4))) float f32x4;

__device__ __forceinline__ short f2bf(float f) {
  union { float f; unsigned u; } v; v.f = f;
  unsigned u = v.u;
  unsigned r = (u + 0x7FFFu + ((u >> 16) & 1u)) >> 16;
  return (short)r;
}

// ---------------------------------------------------------------------------
// Kernel 1: transpose + convert the three weights to bf16.
// Wt layout: [3][H=128][C=1024] bf16 (so GEMM B-stage loads are contiguous).
// ---------------------------------------------------------------------------
__global__ __launch_bounds__(256) void wprep_kernel(
    const float* __restrict__ Wk, const float* __restrict__ Wq,
    const float* __restrict__ Wv, short* __restrict__ Wt) {
  const int NW = C_DIM * H_DIM;
  int idx = blockIdx.x * 256 + threadIdx.x;
  if (idx >= 3 * NW) return;
  int w = idx / NW;
  int rem = idx - w * NW;
  int c = rem >> 7;      // /128
  int h = rem & 127;
  const float* W = (w == 0) ? Wk : ((w == 1) ? Wq : Wv);
  Wt[w * NW + h * C_DIM + c] = f2bf(W[rem]);   // W[c*128+h]
}

// ---------------------------------------------------------------------------
// Kernel 2: projection GEMM.  out[m][h] = sum_c x[m][c] * W[c][h]
// Tile: 128 rows x 128 cols (full N), K staged 32 at a time.
// 4 waves in 2x2; each wave: 64x64 via 4x4 mfma_f32_16x16x32_bf16 tiles.
// wi = 0 -> K (row-major), 1 -> Q (row-major), 2 -> V (stored transposed [h][t])
// ---------------------------------------------------------------------------
__global__ __launch_bounds__(256) void proj_kernel(
    const float* __restrict__ x, const short* __restrict__ Wt,
    short* __restrict__ Kb, short* __restrict__ Qb, short* __restrict__ Vt) {
  const int wi = blockIdx.y;
  const int m0 = blockIdx.x * 128;
  // pitch 40 elems = 80 B: 16B-aligned rows, 2-way (free) bank aliasing
  __shared__ short As[128][40];
  __shared__ short Bs[128][40];
  const int tid  = threadIdx.x;
  const int lane = tid & 63;
  const int wv   = tid >> 6;
  const int n    = lane & 15;
  const int quad = lane >> 4;
  const int mbase = (wv >> 1) * 64;
  const int nbase = (wv & 1) * 64;
  const short* Wp = Wt + wi * (C_DIM * H_DIM);

  const int srow = tid >> 1;          // 0..127
  const int scol = (tid & 1) * 16;    // 0 or 16

  f32x4 acc[4][4];
#pragma unroll
  for (int i = 0; i < 4; i++)
#pragma unroll
    for (int j = 0; j < 4; j++) {
      f32x4 z = {0.f, 0.f, 0.f, 0.f};
      acc[i][j] = z;
    }

  for (int k0 = 0; k0 < C_DIM; k0 += 32) {
    __syncthreads();
    {
      // stage A: x fp32 -> bf16, 16 floats/thread
      const float* src = x + (size_t)(m0 + srow) * C_DIM + k0 + scol;
      float4 f0 = ((const float4*)src)[0];
      float4 f1 = ((const float4*)src)[1];
      float4 f2 = ((const float4*)src)[2];
      float4 f3 = ((const float4*)src)[3];
      __attribute__((aligned(16))) short tmp[16];
      tmp[0] = f2bf(f0.x); tmp[1] = f2bf(f0.y); tmp[2] = f2bf(f0.z); tmp[3] = f2bf(f0.w);
      tmp[4] = f2bf(f1.x); tmp[5] = f2bf(f1.y); tmp[6] = f2bf(f1.z); tmp[7] = f2bf(f1.w);
      tmp[8] = f2bf(f2.x); tmp[9] = f2bf(f2.y); tmp[10] = f2bf(f2.z); tmp[11] = f2bf(f2.w);
      tmp[12] = f2bf(f3.x); tmp[13] = f2bf(f3.y); tmp[14] = f2bf(f3.z); tmp[15] = f2bf(f3.w);
      ((int4*)&As[srow][scol])[0] = ((int4*)tmp)[0];
      ((int4*)&As[srow][scol])[1] = ((int4*)tmp)[1];
      // stage B: Wt bf16, contiguous 32 B/thread
      const short* wsrc = Wp + (size_t)srow * C_DIM + k0 + scol;
      ((int4*)&Bs[srow][scol])[0] = ((const int4*)wsrc)[0];
      ((int4*)&Bs[srow][scol])[1] = ((const int4*)wsrc)[1];
    }
    __syncthreads();

    bf16x8 aF[4], bF[4];
#pragma unroll
    for (int mt = 0; mt < 4; mt++)
      aF[mt] = *(const bf16x8*)&As[mbase + mt * 16 + n][quad * 8];
#pragma unroll
    for (int nt = 0; nt < 4; nt++)
      bF[nt] = *(const bf16x8*)&Bs[nbase + nt * 16 + n][quad * 8];
#pragma unroll
    for (int mt = 0; mt < 4; mt++)
#pragma unroll
      for (int nt = 0; nt < 4; nt++)
        acc[mt][nt] = __builtin_amdgcn_mfma_f32_16x16x32_bf16(
            aF[mt], bF[nt], acc[mt][nt], 0, 0, 0);
  }

  // epilogue: C/D layout col = lane&15, row = quad*4 + reg
#pragma unroll
  for (int mt = 0; mt < 4; mt++) {
#pragma unroll
    for (int nt = 0; nt < 4; nt++) {
#pragma unroll
      for (int i = 0; i < 4; i++) {
        int row = m0 + mbase + mt * 16 + quad * 4 + i;   // token index
        int col = nbase + nt * 16 + n;                   // h index
        short v = f2bf(acc[mt][nt][i]);
        if (wi == 0) {
          Kb[(size_t)row * H_DIM + col] = v;
        } else if (wi == 1) {
          Qb[(size_t)row * H_DIM + col] = v;
        } else {
          int bb = row >> 11;
          int t = row & (T_DIM - 1);
          Vt[((size_t)bb * H_DIM + col) * T_DIM + t] = v;
        }
      }
    }
  }
}

// ---------------------------------------------------------------------------
// Kernel 3: causal flash attention.
// Block = 256 threads (4 waves). BM = 64 Q-rows (16/wave), BN = 64 KV cols.
// Q A-frags register-resident; K,V^T staged in LDS; P via LDS round-trip.
// ---------------------------------------------------------------------------
__global__ __launch_bounds__(256) void attn_kernel(
    const short* __restrict__ Qb, const short* __restrict__ Kb,
    const short* __restrict__ Vt, float* __restrict__ out) {
  const int b  = blockIdx.y;
  const int q0 = blockIdx.x * 64;
  const int tid  = threadIdx.x;
  const int lane = tid & 63;
  const int wv   = tid >> 6;
  const int n    = lane & 15;
  const int quad = lane >> 4;

  __shared__ short Ks[64][136];     // pitch 272 B: aligned, ~2-way
  __shared__ short Vs[128][72];     // pitch 144 B
  __shared__ short Ps[4][16][72];   // per-wave P strips

  // Q A-frags: A[m = lane&15][k = quad*8+j], rows q0 + wv*16 + n
  bf16x8 aQ[4];
  {
    const short* qrow = Qb + (size_t)(b * T_DIM + q0 + wv * 16 + n) * H_DIM;
#pragma unroll
    for (int kc = 0; kc < 4; kc++)
      aQ[kc] = *(const bf16x8*)(qrow + kc * 32 + quad * 8);
  }

  f32x4 accO[8];
#pragma unroll
  for (int i = 0; i < 8; i++) {
    f32x4 z = {0.f, 0.f, 0.f, 0.f};
    accO[i] = z;
  }
  float mrow[4] = {-1e30f, -1e30f, -1e30f, -1e30f};
  float lrow[4] = {0.f, 0.f, 0.f, 0.f};
  const float scale = 0.08838834764831845f;  // 1/sqrt(128)
  const int row0 = q0 + wv * 16 + quad * 4;  // + reg i

  for (int j0 = 0; j0 <= q0; j0 += 64) {
    __syncthreads();
    // stage K tile: 64 rows x 128 h
#pragma unroll
    for (int p = 0; p < 4; p++) {
      int cid = tid + p * 256;
      int row = cid >> 4, c16 = cid & 15;
      *(int4*)&Ks[row][c16 * 8] =
          *(const int4*)(Kb + (size_t)(b * T_DIM + j0 + row) * H_DIM + c16 * 8);
    }
    // stage V^T tile: 128 h x 64 t
#pragma unroll
    for (int p = 0; p < 4; p++) {
      int cid = tid + p * 256;
      int h = cid >> 3, c8 = cid & 7;
      *(int4*)&Vs[h][c8 * 8] =
          *(const int4*)(Vt + ((size_t)b * H_DIM + h) * T_DIM + j0 + c8 * 8);
    }
    __syncthreads();

    // S = Q K^T  (per wave: 16 x 64, 4 n-tiles)
    f32x4 accS[4];
#pragma unroll
    for (int nt = 0; nt < 4; nt++) {
      f32x4 z = {0.f, 0.f, 0.f, 0.f};
      accS[nt] = z;
    }
#pragma unroll
    for (int nt = 0; nt < 4; nt++)
#pragma unroll
      for (int kc = 0; kc < 4; kc++) {
        bf16x8 bK = *(const bf16x8*)&Ks[nt * 16 + n][kc * 32 + quad * 8];
        accS[nt] = __builtin_amdgcn_mfma_f32_16x16x32_bf16(aQ[kc], bK, accS[nt], 0, 0, 0);
      }

    // scale + causal mask + online softmax (C layout: col = lane&15, row = quad*4+i)
    float sv[4][4];
    float mt4[4] = {-1e30f, -1e30f, -1e30f, -1e30f};
#pragma unroll
    for (int nt = 0; nt < 4; nt++) {
      int col = j0 + nt * 16 + n;
#pragma unroll
      for (int i = 0; i < 4; i++) {
        float s = accS[nt][i] * scale;
        if (col > row0 + i) s = -1e30f;
        sv[nt][i] = s;
        mt4[i] = fmaxf(mt4[i], s);
      }
    }
#pragma unroll
    for (int i = 0; i < 4; i++) {
#pragma unroll
      for (int off = 1; off < 16; off <<= 1)
        mt4[i] = fmaxf(mt4[i], __shfl_xor(mt4[i], off, 64));
    }
    float alpha[4], rsum[4];
#pragma unroll
    for (int i = 0; i < 4; i++) {
      float mnew = fmaxf(mrow[i], mt4[i]);
      alpha[i] = __expf(mrow[i] - mnew);
      mrow[i] = mnew;
      rsum[i] = 0.f;
    }
#pragma unroll
    for (int nt = 0; nt < 4; nt++)
#pragma unroll
      for (int i = 0; i < 4; i++) {
        float p = __expf(sv[nt][i] - mrow[i]);
        rsum[i] += p;
        Ps[wv][quad * 4 + i][nt * 16 + n] = f2bf(p);
      }
#pragma unroll
    for (int i = 0; i < 4; i++) {
#pragma unroll
      for (int off = 1; off < 16; off <<= 1)
        rsum[i] += __shfl_xor(rsum[i], off, 64);
      lrow[i] = lrow[i] * alpha[i] + rsum[i];
    }
#pragma unroll
    for (int ht = 0; ht < 8; ht++)
#pragma unroll
      for (int i = 0; i < 4; i++)
        accO[ht][i] *= alpha[i];

    __syncthreads();  // P strips visible (also orders LDS within wave)

    // O += P V  (P in A-layout from LDS; V B-frags contiguous from Vs)
    bf16x8 aP[2];
#pragma unroll
    for (int kc = 0; kc < 2; kc++)
      aP[kc] = *(const bf16x8*)&Ps[wv][n][kc * 32 + quad * 8];
#pragma unroll
    for (int ht = 0; ht < 8; ht++)
#pragma unroll
      for (int kc = 0; kc < 2; kc++) {
        bf16x8 bV = *(const bf16x8*)&Vs[ht * 16 + n][kc * 32 + quad * 8];
        accO[ht] = __builtin_amdgcn_mfma_f32_16x16x32_bf16(aP[kc], bV, accO[ht], 0, 0, 0);
      }
  }

  // epilogue: out fp32 [b][t][h]
#pragma unroll
  for (int i = 0; i < 4; i++) {
    float inv = 1.0f / lrow[i];
    size_t base = (size_t)(b * T_DIM + row0 + i) * H_DIM;
#pragma unroll
    for (int ht = 0; ht < 8; ht++)
      out[base + ht * 16 + n] = accO[ht][i] * inv;
  }
}

// ---------------------------------------------------------------------------
extern "C" void kernel_launch(void* const* d_in, const int* in_sizes, int n_in,
                              void* d_out, int out_size, void* d_ws, size_t ws_size,
                              hipStream_t stream) {
  (void)in_sizes; (void)n_in; (void)out_size; (void)ws_size;
  const float* x  = (const float*)d_in[0];
  const float* Wk = (const float*)d_in[1];
  const float* Wq = (const float*)d_in[2];
  const float* Wv = (const float*)d_in[3];
  float* out = (float*)d_out;

  char* ws = (char*)d_ws;
  short* Wt = (short*)ws;                              // 3*128*1024*2 = 786432 B
  short* Kb = (short*)(ws + 786432);                   // 16384*128*2 = 4 MB
  short* Qb = (short*)(ws + 786432 + 4194304);         // 4 MB
  short* Vt = (short*)(ws + 786432 + 8388608);         // [8][128][2048] bf16, 4 MB

  wprep_kernel<<<dim3(1536), dim3(256), 0, stream>>>(Wk, Wq, Wv, Wt);
  proj_kernel<<<dim3(128, 3), dim3(256), 0, stream>>>(x, Wt, Kb, Qb, Vt);
  attn_kernel<<<dim3(T_DIM / 64, B_DIM), dim3(256), 0, stream>>>(Qb, Kb, Vt, out);
}